// Round 20
// baseline (377.399 us; speedup 1.0000x reference)
//
#include <hip/hip_runtime.h>
#include <hip/hip_fp16.h>

#define N_DRUG 20000
#define N_DIS  10000
#define N_ATTR 2000
#define T_ATTR 8
#define E_MT   500000
#define E_HA   100000
#define E_LBL  200000
#define HC     128
#define BPW    5000
#define NSS    46
#define NBMAX  80

__device__ __forceinline__ float leakyf(float x) { return x >= 0.f ? x : 0.01f * x; }

__device__ __forceinline__ unsigned short f2bf(float f) {
  unsigned int u = __float_as_uint(f);
  return (unsigned short)((u + 0x7fffu + ((u >> 16) & 1u)) >> 16);
}
__device__ __forceinline__ float bflo(unsigned int u) { return __uint_as_float(u << 16); }
__device__ __forceinline__ float bfhi(unsigned int u) { return __uint_as_float(u & 0xffff0000u); }

typedef __attribute__((ext_vector_type(8))) short bf16x8;
typedef __attribute__((ext_vector_type(4))) float f32x4;
typedef __attribute__((ext_vector_type(2))) float f32x2;

__device__ __forceinline__ unsigned int pk_fp8x4(float a, float b, float c, float d) {
  int w = 0;
  w = __builtin_amdgcn_cvt_pk_fp8_f32(a, b, w, false);
  w = __builtin_amdgcn_cvt_pk_fp8_f32(c, d, w, true);
  return (unsigned int)w;
}

// ---------------- CSR build ----------------
#define HB0 0
#define HB1 800000
#define HB2(t) (2400000 + (t) * 32000)
#define HB10(t) (2656000 + (t) * 320000)
#define HTOT 5216000
#define WB0 0
#define WB1 10000
#define WB2(t) (30000 + (t) * 2000)
#define WB10(t) (46000 + (t) * 20000)
#define WTOT 206000
#define OFF_Z0 0
#define OFF_D  10001
#define OFF_Z2(t) (190002 + (t) * 2001)
#define OFF_TOT 206010
#define SCH 2048
#define SMAXC 128

struct SegB { int bins; int hbase; int wbase; int obase; int ostride; int nbz; };
__device__ __forceinline__ SegB segb(int z) {
  SegB s;
  if (z == 0)      { s.bins = N_DIS;  s.hbase = HB0;  s.wbase = WB0;  s.obase = OFF_Z0;    s.ostride = 1; s.nbz = NBMAX; }
  else if (z == 1) { s.bins = N_DRUG; s.hbase = HB1;  s.wbase = WB1;  s.obase = OFF_D;     s.ostride = 9; s.nbz = NBMAX; }
  else if (z < 10) { int t = z - 2;  s.bins = N_ATTR; s.hbase = HB2(t);  s.wbase = WB2(t);  s.obase = OFF_Z2(t);   s.ostride = 1; s.nbz = 16; }
  else             { int t = z - 10; s.bins = N_DRUG; s.hbase = HB10(t); s.wbase = WB10(t); s.obase = OFF_D + 1 + t; s.ostride = 9; s.nbz = 16; }
  return s;
}

struct SegE { const int* key; const int* oth; int n; int roff; int* val; };
__device__ __forceinline__ SegE sege(int z,
    const int* mt_src, const int* mt_dst, const int* ha_src, const int* ha_dst,
    int* vmd, int* vdrug, int* vhd) {
  SegE s;
  if (z == 0)      { s.key = mt_dst; s.oth = mt_src; s.n = E_MT; s.roff = 0; s.val = vmd; }
  else if (z == 1) { s.key = mt_src; s.oth = mt_dst; s.n = E_MT; s.roff = 0; s.val = vdrug; }
  else if (z < 10) { int t = z - 2;
    s.key = ha_dst + (size_t)t * E_HA; s.oth = ha_src + (size_t)t * E_HA; s.n = E_HA;
    s.roff = 0; s.val = vhd + (size_t)t * E_HA; }
  else { int t = z - 10;
    s.key = ha_src + (size_t)t * E_HA; s.oth = ha_dst + (size_t)t * E_HA; s.n = E_HA;
    s.roff = 10000 + t * N_ATTR; s.val = vdrug; }
  return s;
}

__device__ __forceinline__ void ss_resolve(int ss, int& z, int& klo) {
  if (ss < 2)       { z = 0; klo = ss * BPW; }
  else if (ss < 6)  { z = 1; klo = (ss - 2) * BPW; }
  else if (ss < 14) { z = 2 + (ss - 6); klo = 0; }
  else              { z = 10 + ((ss - 14) >> 2); klo = ((ss - 14) & 3) * BPW; }
}

__global__ __launch_bounds__(256) void k_hist(
    const int* __restrict__ mt_src, const int* __restrict__ mt_dst,
    const int* __restrict__ ha_src, const int* __restrict__ ha_dst,
    int* __restrict__ hist) {
  int z, klo;
  ss_resolve(blockIdx.z, z, klo);
  SegB g = segb(z);
  int b = blockIdx.x;
  if (b >= g.nbz) return;
  SegE s = sege(z, mt_src, mt_dst, ha_src, ha_dst, nullptr, nullptr, nullptr);
  int window = min(BPW, g.bins - klo);
  __shared__ int h[BPW];
  int tid = threadIdx.x;
  for (int i = tid; i < window; i += 256) h[i] = 0;
  __syncthreads();
  int ch = (s.n + g.nbz - 1) / g.nbz;
  int lo = b * ch, hi = min(s.n, lo + ch);
  for (int i = lo + tid; i < hi; i += 256) {
    int r = s.key[i] - klo;
    if ((unsigned)r < (unsigned)window) atomicAdd(&h[r], 1);
  }
  __syncthreads();
  int* hz = hist + g.hbase + (size_t)b * g.bins + klo;
  for (int i = tid; i < window; i += 256) hz[i] = h[i];
}

__global__ __launch_bounds__(256) void k_blkpfx(int* __restrict__ hist, int* __restrict__ off,
                                                unsigned short* __restrict__ wtab) {
  SegB g = segb(blockIdx.z);
  int i = blockIdx.x * 256 + threadIdx.x;
  if (i >= g.bins) return;
  int run = 0;
  for (int b = 0; b < g.nbz; b++) {
    int idx = g.hbase + b * g.bins + i;
    int v = hist[idx];
    hist[idx] = run;
    run += v;
  }
  off[g.obase + i * g.ostride] = run;
  __half hw = __float2half(1.0f / (float)(run > 0 ? run : 1));
  wtab[g.wbase + i] = __half_as_ushort(hw);
}

__device__ __forceinline__ void scan_region(int r, int& base, int& L) {
  if (r == 0)      { base = OFF_Z0; L = 10000; }
  else if (r == 1) { base = OFF_D;  L = 180000; }
  else             { int t = r - 2; base = OFF_Z2(t); L = 2000; }
}

__global__ __launch_bounds__(256) void k_scan_l1(int* __restrict__ off, int* __restrict__ csum) {
  int base, L;
  scan_region(blockIdx.y, base, L);
  int c = blockIdx.x;
  int c0 = c * SCH;
  if (c0 >= L) return;
  int tid = threadIdx.x;
  int i0 = c0 + tid * 8;
  int v[8];
  int s = 0;
  #pragma unroll
  for (int j = 0; j < 8; j++) {
    int i = i0 + j;
    v[j] = (i < L) ? off[base + i] : 0;
    s += v[j];
  }
  __shared__ int ssum[256];
  ssum[tid] = s;
  __syncthreads();
  if (tid == 0) {
    int run = 0;
    #pragma unroll 8
    for (int i = 0; i < 256; i++) { int x = ssum[i]; ssum[i] = run; run += x; }
    csum[blockIdx.y * SMAXC + c] = run;
  }
  __syncthreads();
  int run = ssum[tid];
  #pragma unroll
  for (int j = 0; j < 8; j++) {
    int i = i0 + j;
    if (i < L) { off[base + i] = run; run += v[j]; }
  }
}

__global__ void k_scan_l2(int* __restrict__ off, int* __restrict__ csum) {
  int r = blockIdx.x;
  int base, L;
  scan_region(r, base, L);
  if (threadIdx.x == 0) {
    int nc = (L + SCH - 1) / SCH;
    int run = 0;
    for (int c = 0; c < nc; c++) {
      int v = csum[r * SMAXC + c];
      csum[r * SMAXC + c] = run;
      run += v;
    }
    off[base + L] = run;
  }
}

__global__ __launch_bounds__(256) void k_scan_l3(int* __restrict__ off, const int* __restrict__ csum) {
  int base, L;
  scan_region(blockIdx.y, base, L);
  int c = blockIdx.x;
  int c0 = c * SCH;
  if (c0 >= L || c == 0) return;
  int add = csum[blockIdx.y * SMAXC + c];
  int i0 = c0 + threadIdx.x * 8;
  #pragma unroll
  for (int j = 0; j < 8; j++) {
    int i = i0 + j;
    if (i < L) off[base + i] += add;
  }
}

__global__ __launch_bounds__(256) void k_fill2(
    const int* __restrict__ mt_src, const int* __restrict__ mt_dst,
    const int* __restrict__ ha_src, const int* __restrict__ ha_dst,
    const int* __restrict__ hist, const int* __restrict__ off,
    const unsigned short* __restrict__ wtab,
    int* vmd, int* vdrug, int* vhd) {
  int z, klo;
  ss_resolve(blockIdx.z, z, klo);
  SegB g = segb(z);
  int b = blockIdx.x;
  if (b >= g.nbz) return;
  SegE s = sege(z, mt_src, mt_dst, ha_src, ha_dst, vmd, vdrug, vhd);
  int window = min(BPW, g.bins - klo);
  __shared__ int h[BPW];
  __shared__ unsigned short hw[BPW];
  int tid = threadIdx.x;
  const int* hz = hist + g.hbase + (size_t)b * g.bins + klo;
  for (int i = tid; i < window; i += 256) {
    h[i] = hz[i] + off[g.obase + (klo + i) * g.ostride];
    hw[i] = wtab[g.wbase + klo + i];
  }
  __syncthreads();
  int ch = (s.n + g.nbz - 1) / g.nbz;
  int lo = b * ch, hi = min(s.n, lo + ch);
  for (int i = lo + tid; i < hi; i += 256) {
    int r = s.key[i] - klo;
    if ((unsigned)r < (unsigned)window) {
      int pos = atomicAdd(&h[r], 1);
      s.val[pos] = (int)(((unsigned int)hw[r] << 16) | (unsigned int)(s.oth[i] + s.roff));
    }
  }
}

// ---------------- x_dis init (dual f32 + bf16) ----------------
__global__ void k_dis0(const float* __restrict__ dx, const float* __restrict__ w,
                       const float* __restrict__ b, const float* __restrict__ emb,
                       float* __restrict__ out, unsigned short* __restrict__ outb) {
  int i = blockIdx.x;
  int j = threadIdx.x;
  float s = b[j] + emb[(size_t)i * HC + j];
  #pragma unroll
  for (int k = 0; k < 10; k++) s += dx[i * 10 + k] * w[k * HC + j];
  out[(size_t)i * HC + j] = s;
  outb[(size_t)i * HC + j] = f2bf(s);
}

// ---------------- Wct + biasc (both layers) ----------------
__global__ void k_wc(const float* __restrict__ rmt_wr, const float* __restrict__ rha_wr,
                     const float* __restrict__ rmt_bl, const float* __restrict__ rha_bl,
                     unsigned short* __restrict__ Wct, float* __restrict__ biasc) {
  int l = blockIdx.y;
  const float* wr_main = rmt_wr + (size_t)l * HC * HC;
  const float* wr_t = rha_wr + (size_t)l * T_ATTR * HC * HC;
  const float* bl_main = rmt_bl + (size_t)l * HC;
  const float* bl_t = rha_bl + (size_t)l * T_ATTR * HC;
  unsigned short* Wo = Wct + (size_t)l * 16384;
  float* bo = biasc + (size_t)l * 128;
  int i = blockIdx.x * blockDim.x + threadIdx.x;
  if (i < HC * HC) {
    float s = wr_main[i];
    #pragma unroll
    for (int t = 0; t < T_ATTR; t++) s += wr_t[(size_t)t * HC * HC + i];
    int k = i >> 7, n = i & 127;
    Wo[n * 128 + k] = f2bf(s);
  }
  if (i < HC) {
    float s = bl_main[i];
    #pragma unroll
    for (int t = 0; t < T_ATTR; t++) s += bl_t[t * HC + i];
    bo[i] = s;
  }
}

// ---------------- weight transpose f32 [128][128] -> bf16 Wt[n][k], 54 mats ----------------
struct WtJobs { const float* s[54]; };
__global__ __launch_bounds__(256) void k_wt(WtJobs J, unsigned short* __restrict__ dst) {
  const float* src = J.s[blockIdx.z];
  unsigned short* d = dst + (size_t)blockIdx.z * 16384;
  __shared__ float t[32][33];
  int tx = threadIdx.x & 31, ty = threadIdx.x >> 5;
  int i0 = blockIdx.x * 32, j0 = blockIdx.y * 32;
  #pragma unroll
  for (int q = 0; q < 4; q++) {
    int k = i0 + ty + q * 8;
    t[ty + q * 8][tx] = src[k * 128 + j0 + tx];
  }
  __syncthreads();
  #pragma unroll
  for (int q = 0; q < 4; q++) {
    int n = j0 + ty + q * 8;
    d[(size_t)n * 128 + i0 + tx] = f2bf(t[tx][ty + q * 8]);
  }
}

// ---------------- f32 -> bf16 convert ----------------
__global__ __launch_bounds__(256) void k_cvt(const float* __restrict__ src,
                                             unsigned short* __restrict__ dst, int n4) {
  int i = blockIdx.x * 256 + threadIdx.x;
  if (i >= n4) return;
  float4 v = ((const float4*)src)[i];
  uint2 w;
  w.x = (unsigned int)f2bf(v.x) | ((unsigned int)f2bf(v.y) << 16);
  w.y = (unsigned int)f2bf(v.z) | ((unsigned int)f2bf(v.w) << 16);
  ((uint2*)dst)[i] = w;
}

// ---------------- f32 -> bf16 + fp8 dual convert (one read) ----------------
__global__ __launch_bounds__(256) void k_cvt_dual(const float* __restrict__ src,
                                                  unsigned short* __restrict__ dstb,
                                                  unsigned char* __restrict__ dst8, int n4) {
  int i = blockIdx.x * 256 + threadIdx.x;
  if (i >= n4) return;
  float4 v = ((const float4*)src)[i];
  uint2 w;
  w.x = (unsigned int)f2bf(v.x) | ((unsigned int)f2bf(v.y) << 16);
  w.y = (unsigned int)f2bf(v.z) | ((unsigned int)f2bf(v.w) << 16);
  ((uint2*)dstb)[i] = w;
  ((unsigned int*)dst8)[i] = pk_fp8x4(v.x, v.y, v.z, v.w);
}

// ---------------- 2-edge-per-wave gather accumulators (fp8 tables) ----------------
__device__ __forceinline__ void gacc2_w(const unsigned char* __restrict__ T, const int* __restrict__ val,
                                        int b, int e, int lane31, int slot, f32x4& a) {
  int i = b;
  for (; i + 8 <= e; i += 8) {
    unsigned int pv[4], rv[4];
    #pragma unroll
    for (int q = 0; q < 4; q++) pv[q] = ((const unsigned int*)val)[i + 2 * q + slot];
    #pragma unroll
    for (int q = 0; q < 4; q++)
      rv[q] = *(const unsigned int*)(T + (size_t)(pv[q] & 0xffffu) * HC + lane31 * 4);
    #pragma unroll
    for (int q = 0; q < 4; q++) {
      float w = __half2float(__ushort_as_half((unsigned short)(pv[q] >> 16)));
      f32x2 lo = __builtin_amdgcn_cvt_pk_f32_fp8((int)rv[q], false);
      f32x2 hi = __builtin_amdgcn_cvt_pk_f32_fp8((int)rv[q], true);
      a.x = fmaf(w, lo.x, a.x); a.y = fmaf(w, lo.y, a.y);
      a.z = fmaf(w, hi.x, a.z); a.w = fmaf(w, hi.y, a.w);
    }
  }
  for (int j = i + slot; j < e; j += 2) {
    unsigned int pv = ((const unsigned int*)val)[j];
    unsigned int rv = *(const unsigned int*)(T + (size_t)(pv & 0xffffu) * HC + lane31 * 4);
    float w = __half2float(__ushort_as_half((unsigned short)(pv >> 16)));
    f32x2 lo = __builtin_amdgcn_cvt_pk_f32_fp8((int)rv, false);
    f32x2 hi = __builtin_amdgcn_cvt_pk_f32_fp8((int)rv, true);
    a.x = fmaf(w, lo.x, a.x); a.y = fmaf(w, lo.y, a.y);
    a.z = fmaf(w, hi.x, a.z); a.w = fmaf(w, hi.y, a.w);
  }
}

__device__ __forceinline__ void gacc2_u(const unsigned char* __restrict__ T, const int* __restrict__ val,
                                        int b, int e, int lane31, int slot, f32x4& a) {
  int i = b;
  for (; i + 8 <= e; i += 8) {
    unsigned int pv[4], rv[4];
    #pragma unroll
    for (int q = 0; q < 4; q++) pv[q] = ((const unsigned int*)val)[i + 2 * q + slot];
    #pragma unroll
    for (int q = 0; q < 4; q++)
      rv[q] = *(const unsigned int*)(T + (size_t)(pv[q] & 0xffffu) * HC + lane31 * 4);
    #pragma unroll
    for (int q = 0; q < 4; q++) {
      f32x2 lo = __builtin_amdgcn_cvt_pk_f32_fp8((int)rv[q], false);
      f32x2 hi = __builtin_amdgcn_cvt_pk_f32_fp8((int)rv[q], true);
      a.x += lo.x; a.y += lo.y; a.z += hi.x; a.w += hi.y;
    }
  }
  for (int j = i + slot; j < e; j += 2) {
    unsigned int pv = ((const unsigned int*)val)[j];
    unsigned int rv = *(const unsigned int*)(T + (size_t)(pv & 0xffffu) * HC + lane31 * 4);
    f32x2 lo = __builtin_amdgcn_cvt_pk_f32_fp8((int)rv, false);
    f32x2 hi = __builtin_amdgcn_cvt_pk_f32_fp8((int)rv, true);
    a.x += lo.x; a.y += lo.y; a.z += hi.x; a.w += hi.y;
  }
}

__device__ __forceinline__ void comb32(f32x4& a) {
  a.x += __shfl_xor(a.x, 32);
  a.y += __shfl_xor(a.y, 32);
  a.z += __shfl_xor(a.z, 32);
  a.w += __shfl_xor(a.w, 32);
}

// ---------------- mega segment-mean (drug waves first; fp8 tables; 2 edges/wave) ----------------
__global__ __launch_bounds__(256) void k_seg_mega(
    const int* __restrict__ off, const unsigned short* __restrict__ wtab,
    const int* __restrict__ vmd, const int* __restrict__ vdrug, const int* __restrict__ vhd,
    const unsigned char* __restrict__ xd8, const unsigned char* __restrict__ Ytab8,
    unsigned short* __restrict__ m2disb, float* __restrict__ accd, unsigned short* __restrict__ m2ab) {
  int lane = threadIdx.x & 63;
  int lane31 = lane & 31;
  int slot = lane >> 5;
  int w = blockIdx.x * 4 + (threadIdx.x >> 6);
  if (w < N_DRUG) {
    int d = w;
    int lo = off[OFF_D + d * 9], hi = off[OFF_D + d * 9 + 9];
    f32x4 a = {};
    gacc2_w(Ytab8, vdrug, lo, hi, lane31, slot, a);
    comb32(a);
    if (slot == 0)
      *(float4*)(accd + (size_t)d * HC + lane31 * 4) = make_float4(a.x, a.y, a.z, a.w);
  } else if (w < N_DRUG + N_DIS) {
    int d = w - N_DRUG;
    int lo = off[OFF_Z0 + d], hi = off[OFF_Z0 + d + 1];
    f32x4 a = {};
    gacc2_u(xd8, vmd, lo, hi, lane31, slot, a);
    comb32(a);
    if (slot == 0) {
      float wv = __half2float(__ushort_as_half(wtab[WB0 + d]));
      uint2 o;
      o.x = (unsigned int)f2bf(a.x * wv) | ((unsigned int)f2bf(a.y * wv) << 16);
      o.y = (unsigned int)f2bf(a.z * wv) | ((unsigned int)f2bf(a.w * wv) << 16);
      *(uint2*)(m2disb + (size_t)d * HC + lane31 * 4) = o;
    }
  } else {
    int idx = w - (N_DRUG + N_DIS);
    int t = idx / N_ATTR, r = idx - t * N_ATTR;
    int lo = off[OFF_Z2(t) + r], hi = off[OFF_Z2(t) + r + 1];
    f32x4 a = {};
    gacc2_u(xd8, vhd + (size_t)t * E_HA, lo, hi, lane31, slot, a);
    comb32(a);
    if (slot == 0) {
      float wv = __half2float(__ushort_as_half(wtab[WB2(t) + r]));
      uint2 o;
      o.x = (unsigned int)f2bf(a.x * wv) | ((unsigned int)f2bf(a.y * wv) << 16);
      o.y = (unsigned int)f2bf(a.z * wv) | ((unsigned int)f2bf(a.w * wv) << 16);
      *(uint2*)(m2ab + ((size_t)t * N_ATTR + r) * HC + lane31 * 4) = o;
    }
  }
}

// ---------------- MFMA GEMM ----------------
struct MJob {
  const unsigned short* X1; const unsigned short* Wt1;
  const unsigned short* X2; const unsigned short* Wt2;
  const float* bias; const float* ACC;
  float* D; unsigned short* D2; unsigned char* D3;
  int M; int leaky; int mode;
};
struct MJobs { MJob j[10]; };

__global__ __launch_bounds__(256) void k_gemm_mfma(MJobs jobs) {
  MJob jb = jobs.j[blockIdx.z];
  int m0 = blockIdx.x * 64;
  if (m0 >= jb.M) return;
  int wave = threadIdx.x >> 6;
  int lane = threadIdx.x & 63;
  int l15 = lane & 15, g = lane >> 4;
  int m = m0 + wave * 16 + l15;
  bool mok = m < jb.M;
  int mrow = mok ? m : 0;

  f32x4 acc[8] = {};
  #pragma unroll
  for (int part = 0; part < 2; part++) {
    const unsigned short* X = part ? jb.X2 : jb.X1;
    const unsigned short* Wt = part ? jb.Wt2 : jb.Wt1;
    if (!X) break;
    #pragma unroll
    for (int ks = 0; ks < 4; ks++) {
      int k0 = ks * 32 + g * 8;
      bf16x8 xb = {};
      if (mok) xb = *(const bf16x8*)(X + (size_t)mrow * 128 + k0);
      #pragma unroll
      for (int f = 0; f < 8; f++) {
        bf16x8 wb = *(const bf16x8*)(Wt + (size_t)(f * 16 + l15) * 128 + k0);
        acc[f] = __builtin_amdgcn_mfma_f32_16x16x32_bf16(wb, xb, acc[f], 0, 0, 0);
      }
    }
  }
  if (!mok) return;
  #pragma unroll
  for (int f = 0; f < 8; f++) {
    int n0 = f * 16 + 4 * g;
    float r0 = acc[f][0], r1 = acc[f][1], r2 = acc[f][2], r3 = acc[f][3];
    if (jb.bias) {
      float4 bs = *(const float4*)(jb.bias + n0);
      r0 += bs.x; r1 += bs.y; r2 += bs.z; r3 += bs.w;
    }
    if (jb.ACC) {
      float4 a = *(const float4*)(jb.ACC + (size_t)m * 128 + n0);
      r0 += a.x; r1 += a.y; r2 += a.z; r3 += a.w;
    }
    if (jb.leaky) { r0 = leakyf(r0); r1 = leakyf(r1); r2 = leakyf(r2); r3 = leakyf(r3); }
    if (jb.mode == 1) {
      unsigned short* Db = (unsigned short*)jb.D;
      uint2 w;
      w.x = (unsigned int)f2bf(r0) | ((unsigned int)f2bf(r1) << 16);
      w.y = (unsigned int)f2bf(r2) | ((unsigned int)f2bf(r3) << 16);
      *(uint2*)(Db + (size_t)m * 128 + n0) = w;
    } else if (jb.mode == 2) {
      *(unsigned int*)((unsigned char*)jb.D + (size_t)m * 128 + n0) = pk_fp8x4(r0, r1, r2, r3);
    } else {
      *(float4*)(jb.D + (size_t)m * 128 + n0) = make_float4(r0, r1, r2, r3);
      if (jb.D2) {
        uint2 w;
        w.x = (unsigned int)f2bf(r0) | ((unsigned int)f2bf(r1) << 16);
        w.y = (unsigned int)f2bf(r2) | ((unsigned int)f2bf(r3) << 16);
        *(uint2*)(jb.D2 + (size_t)m * 128 + n0) = w;
      }
      if (jb.D3) {
        *(unsigned int*)(jb.D3 + (size_t)m * 128 + n0) = pk_fp8x4(r0, r1, r2, r3);
      }
    }
  }
}

// ---------------- classifier head GEMMs (bf16 output for tail) ----------------
struct G64Job { const float* X; const float* W; const float* bias; unsigned short* D; int M; };

__global__ __launch_bounds__(256) void k_gemm64(G64Job j0, G64Job j1) {
  G64Job jb = blockIdx.z ? j1 : j0;
  int m0 = blockIdx.x * 64;
  if (m0 >= jb.M) return;
  __shared__ float As[16][68];
  __shared__ float Bs[16][68];
  int tid = threadIdx.x;
  int tx = tid & 15, ty = tid >> 4;
  float acc[4][4];
  #pragma unroll
  for (int i = 0; i < 4; i++)
    #pragma unroll
    for (int j = 0; j < 4; j++) acc[i][j] = 0.f;

  for (int kk = 0; kk < 128; kk += 16) {
    {
      int r = tid >> 2, kq = (tid & 3) * 4;
      int gr = m0 + r;
      float4 v = make_float4(0.f, 0.f, 0.f, 0.f);
      if (gr < jb.M) v = *(const float4*)(jb.X + (size_t)gr * HC + kk + kq);
      As[kq + 0][r] = v.x; As[kq + 1][r] = v.y; As[kq + 2][r] = v.z; As[kq + 3][r] = v.w;
    }
    {
      int k = tid >> 4, c = (tid & 15) * 4;
      *(float4*)&Bs[k][c] = *(const float4*)(jb.W + (size_t)(kk + k) * 64 + c);
    }
    __syncthreads();
    #pragma unroll
    for (int k = 0; k < 16; k++) {
      float4 a = *(const float4*)&As[k][ty * 4];
      float4 b = *(const float4*)&Bs[k][tx * 4];
      float av[4] = {a.x, a.y, a.z, a.w};
      float bb[4] = {b.x, b.y, b.z, b.w};
      #pragma unroll
      for (int i = 0; i < 4; i++)
        #pragma unroll
        for (int j = 0; j < 4; j++) acc[i][j] += av[i] * bb[j];
    }
    __syncthreads();
  }
  float4 bs = make_float4(0.f, 0.f, 0.f, 0.f);
  if (jb.bias) bs = *(const float4*)(jb.bias + tx * 4);
  #pragma unroll
  for (int i = 0; i < 4; i++) {
    int gr = m0 + ty * 4 + i;
    if (gr < jb.M) {
      uint2 w;
      w.x = (unsigned int)f2bf(acc[i][0] + bs.x) | ((unsigned int)f2bf(acc[i][1] + bs.y) << 16);
      w.y = (unsigned int)f2bf(acc[i][2] + bs.z) | ((unsigned int)f2bf(acc[i][3] + bs.w) << 16);
      *(uint2*)(jb.D + (size_t)gr * 64 + tx * 4) = w;
    }
  }
}

// ---------------- per-edge tail MLP: 2 threads/edge (fixed half-row loads) ----------------
__global__ __launch_bounds__(256) void k_tail(
    const unsigned short* __restrict__ U, const unsigned short* __restrict__ V,
    const int* __restrict__ es, const int* __restrict__ ed,
    const float* __restrict__ cw1, const float* __restrict__ cb1,
    const float* __restrict__ cw2, const float* __restrict__ cb2,
    const float* __restrict__ cw3, const float* __restrict__ cb3,
    const float* __restrict__ cw4, const float* __restrict__ cb4,
    float* __restrict__ out, int n) {
  int tid = threadIdx.x;
  int gidx = blockIdx.x * 256 + tid;
  int i = gidx >> 1;          // edge
  int q = gidx & 1;           // feature-half (0: h1[0..31], 1: h1[32..63])
  bool ok = i < n;
  int ii = ok ? i : 0;
  // hoisted loads: edge ids then U/V half-rows (4 uint4 = 32 bf16 each)
  int s = es[ii], d = ed[ii];
  const uint4* up = (const uint4*)(U + (size_t)s * 64) + q * 4;
  const uint4* vp = (const uint4*)(V + (size_t)d * 64) + q * 4;
  uint4 ua[4], va[4];
  #pragma unroll
  for (int p = 0; p < 4; p++) { ua[p] = up[p]; va[p] = vp[p]; }

  __shared__ float w1[64 * 32];
  __shared__ float w2[32 * 16];
  __shared__ float w3[16 * 8];
  __shared__ float w4[8];
  __shared__ float b1[32], b2[16], b3[8];
  #pragma unroll
  for (int p = 0; p < 8; p++) w1[tid + p * 256] = cw1[tid + p * 256];
  #pragma unroll
  for (int p = 0; p < 2; p++) w2[tid + p * 256] = cw2[tid + p * 256];
  if (tid < 128) w3[tid] = cw3[tid];
  if (tid < 8)  w4[tid] = cw4[tid];
  if (tid < 32) b1[tid] = cb1[tid];
  if (tid < 16) b2[tid] = cb2[tid];
  if (tid < 8)  b3[tid] = cb3[tid];
  __syncthreads();
  if (!ok) return;

  // h1 half: 32 features (8 bf16 per uint4 x 4)
  float h1h[32];
  #pragma unroll
  for (int p = 0; p < 4; p++) {
    uint4 a = ua[p], b = va[p];
    h1h[8 * p + 0] = leakyf(bflo(a.x) + bflo(b.x));
    h1h[8 * p + 1] = leakyf(bfhi(a.x) + bfhi(b.x));
    h1h[8 * p + 2] = leakyf(bflo(a.y) + bflo(b.y));
    h1h[8 * p + 3] = leakyf(bfhi(a.y) + bfhi(b.y));
    h1h[8 * p + 4] = leakyf(bflo(a.z) + bflo(b.z));
    h1h[8 * p + 5] = leakyf(bfhi(a.z) + bfhi(b.z));
    h1h[8 * p + 6] = leakyf(bflo(a.w) + bflo(b.w));
    h1h[8 * p + 7] = leakyf(bfhi(a.w) + bfhi(b.w));
  }
  // partial h2 over this half's k range (k = q*32 + 0..31)
  float h2[32];
  #pragma unroll
  for (int j = 0; j < 32; j++) h2[j] = 0.f;
  #pragma unroll
  for (int k = 0; k < 32; k++) {
    float hv = h1h[k];
    const float* wr = &w1[(q * 32 + k) * 32];
    #pragma unroll
    for (int jq = 0; jq < 8; jq++) {
      float4 w = *(const float4*)&wr[jq * 4];
      h2[4 * jq + 0] = fmaf(hv, w.x, h2[4 * jq + 0]);
      h2[4 * jq + 1] = fmaf(hv, w.y, h2[4 * jq + 1]);
      h2[4 * jq + 2] = fmaf(hv, w.z, h2[4 * jq + 2]);
      h2[4 * jq + 3] = fmaf(hv, w.w, h2[4 * jq + 3]);
    }
  }
  // combine halves (lane pair) and add bias
  #pragma unroll
  for (int j = 0; j < 32; j++) {
    h2[j] += __shfl_xor(h2[j], 1);
    h2[j] += b1[j];
  }
  float h3[16];
  #pragma unroll
  for (int j = 0; j < 16; j++) h3[j] = b2[j];
  #pragma unroll
  for (int k = 0; k < 32; k++) {
    float hv = leakyf(h2[k]);
    #pragma unroll
    for (int jq = 0; jq < 4; jq++) {
      float4 w = *(const float4*)&w2[k * 16 + jq * 4];
      h3[4 * jq + 0] = fmaf(hv, w.x, h3[4 * jq + 0]);
      h3[4 * jq + 1] = fmaf(hv, w.y, h3[4 * jq + 1]);
      h3[4 * jq + 2] = fmaf(hv, w.z, h3[4 * jq + 2]);
      h3[4 * jq + 3] = fmaf(hv, w.w, h3[4 * jq + 3]);
    }
  }
  if (q) return;
  float h4[8];
  #pragma unroll
  for (int j = 0; j < 8; j++) h4[j] = b3[j];
  #pragma unroll
  for (int k = 0; k < 16; k++) {
    float hv = leakyf(h3[k]);
    #pragma unroll
    for (int jq = 0; jq < 2; jq++) {
      float4 w = *(const float4*)&w3[k * 8 + jq * 4];
      h4[4 * jq + 0] = fmaf(hv, w.x, h4[4 * jq + 0]);
      h4[4 * jq + 1] = fmaf(hv, w.y, h4[4 * jq + 1]);
      h4[4 * jq + 2] = fmaf(hv, w.z, h4[4 * jq + 2]);
      h4[4 * jq + 3] = fmaf(hv, w.w, h4[4 * jq + 3]);
    }
  }
  float p = cb4[0];
  #pragma unroll
  for (int k = 0; k < 8; k++) p = fmaf(leakyf(h4[k]), w4[k], p);
  out[i] = p;
}

extern "C" void kernel_launch(void* const* d_in, const int* in_sizes, int n_in,
                              void* d_out, int out_size, void* d_ws, size_t ws_size,
                              hipStream_t stream) {
  const float* disease_x   = (const float*)d_in[0];
  const float* drug_emb    = (const float*)d_in[1];
  const float* disease_emb = (const float*)d_in[2];
  const float* attr_emb    = (const float*)d_in[3];
  const float* dis_lin_w   = (const float*)d_in[4];
  const float* dis_lin_b   = (const float*)d_in[5];
  const float* mt_wl  = (const float*)d_in[6];
  const float* mt_bl  = (const float*)d_in[7];
  const float* mt_wr  = (const float*)d_in[8];
  const float* rmt_wl = (const float*)d_in[9];
  const float* rmt_bl = (const float*)d_in[10];
  const float* rmt_wr = (const float*)d_in[11];
  const float* ha_wl  = (const float*)d_in[12];
  const float* ha_bl  = (const float*)d_in[13];
  const float* ha_wr  = (const float*)d_in[14];
  const float* rha_wl = (const float*)d_in[15];
  const float* rha_bl = (const float*)d_in[16];
  const float* rha_wr = (const float*)d_in[17];
  const float* cw0 = (const float*)d_in[18];
  const float* cb0 = (const float*)d_in[19];
  const float* cw1 = (const float*)d_in[20];
  const float* cb1 = (const float*)d_in[21];
  const float* cw2 = (const float*)d_in[22];
  const float* cb2 = (const float*)d_in[23];
  const float* cw3 = (const float*)d_in[24];
  const float* cb3 = (const float*)d_in[25];
  const float* cw4 = (const float*)d_in[26];
  const float* cb4 = (const float*)d_in[27];
  const int* mt_src = (const int*)d_in[28];
  const int* mt_dst = (const int*)d_in[29];
  const int* ha_src = (const int*)d_in[30];
  const int* ha_dst = (const int*)d_in[31];
  const int* ell_src = (const int*)d_in[32];
  const int* ell_dst = (const int*)d_in[33];
  float* out = (float*)d_out;

  const long long ATTR_S = (long long)N_ATTR * HC;
  const long long W_S = HC * HC;

  // ---------- workspace carve ----------
  float* fws = (float*)d_ws;
  size_t o = 0;
  float* x_drug = fws + o; o += (size_t)N_DRUG * HC;
  float* x_dis  = fws + o; o += (size_t)N_DIS * HC;
  float* x_attr = fws + o; o += (size_t)T_ATTR * N_ATTR * HC;
  float* accd   = fws + o; o += (size_t)N_DRUG * HC;
  float* biasc  = fws + o; o += 256;
  unsigned short* Ucls = (unsigned short*)(fws + o); o += (size_t)N_DRUG * 64 / 2;
  unsigned short* Vcls = (unsigned short*)(fws + o); o += (size_t)N_DIS * 64 / 2;
  unsigned short* xdb    = (unsigned short*)(fws + o);
  unsigned short* xdisb  = xdb + (size_t)N_DRUG * HC;
  unsigned short* xab    = xdisb + (size_t)N_DIS * HC;
  unsigned short* m2disb = xab + (size_t)T_ATTR * N_ATTR * HC;
  unsigned short* m2ab   = m2disb + (size_t)N_DIS * HC;
  unsigned short* Wts    = m2ab + (size_t)T_ATTR * N_ATTR * HC;
  unsigned short* Wct    = Wts + 54 * 16384;
  unsigned char* Ytab8   = (unsigned char*)(Wct + 2 * 16384);
  unsigned char* Ydis8   = Ytab8;
  unsigned char* Yattr8  = Ytab8 + (size_t)N_DIS * HC;
  unsigned char* xd8     = Ytab8 + (size_t)(N_DIS + T_ATTR * N_ATTR) * HC;
  unsigned char* uchar_end = xd8 + (size_t)N_DRUG * HC;
  o += ((size_t)(uchar_end - (unsigned char*)xdb) + 3) / 4;
  int* iws = (int*)(fws + o);
  int* off = iws;
  int* vmd   = off + OFF_TOT;
  int* vdrug = vmd + E_MT;
  int* vhd   = vdrug + (E_MT + T_ATTR * E_HA);
  unsigned short* wtab = (unsigned short*)(vhd + (size_t)T_ATTR * E_HA);
  int* csum = (int*)(wtab + WTOT + (WTOT & 1));
  int* hist = (int*)fws;

  dim3 b256(256);
  // ---------- CSR build ----------
  k_hist<<<dim3(NBMAX, 1, NSS), b256, 0, stream>>>(mt_src, mt_dst, ha_src, ha_dst, hist);
  k_blkpfx<<<dim3((N_DRUG + 255) / 256, 1, 18), b256, 0, stream>>>(hist, off, wtab);
  {
    dim3 sg((180000 + SCH - 1) / SCH, 10);
    k_scan_l1<<<sg, b256, 0, stream>>>(off, csum);
    k_scan_l2<<<10, 64, 0, stream>>>(off, csum);
    k_scan_l3<<<sg, b256, 0, stream>>>(off, csum);
  }
  k_fill2<<<dim3(NBMAX, 1, NSS), b256, 0, stream>>>(mt_src, mt_dst, ha_src, ha_dst, hist, off, wtab,
                                                    vmd, vdrug, vhd);

  // ---------- weights (both layers, batched) ----------
  k_wc<<<dim3(64, 2), b256, 0, stream>>>(rmt_wr, rha_wr, rmt_bl, rha_bl, Wct, biasc);
  {
    WtJobs W{};
    for (int l = 0; l < 2; l++) {
      int base = l * 27;
      W.s[base + 0] = rmt_wl + (size_t)l * W_S;
      for (int t = 0; t < T_ATTR; t++) W.s[base + 1 + t] = rha_wl + (size_t)l * T_ATTR * W_S + (size_t)t * W_S;
      W.s[base + 9] = mt_wl + (size_t)l * W_S;
      W.s[base + 10] = mt_wr + (size_t)l * W_S;
      for (int t = 0; t < T_ATTR; t++) W.s[base + 11 + t] = ha_wl + (size_t)l * T_ATTR * W_S + (size_t)t * W_S;
      for (int t = 0; t < T_ATTR; t++) W.s[base + 19 + t] = ha_wr + (size_t)l * T_ATTR * W_S + (size_t)t * W_S;
    }
    k_wt<<<dim3(4, 4, 54), b256, 0, stream>>>(W, Wts);
  }

  // ---------- node init + initial bf16/fp8 copies ----------
  k_dis0<<<N_DIS, 128, 0, stream>>>(disease_x, dis_lin_w, dis_lin_b, disease_emb, x_dis, xdisb);
  k_cvt_dual<<<dim3((N_DRUG * HC / 4 + 255) / 256), b256, 0, stream>>>(drug_emb, xdb, xd8, N_DRUG * HC / 4);
  k_cvt<<<dim3((T_ATTR * N_ATTR * HC / 4 + 255) / 256), b256, 0, stream>>>(attr_emb, xab, T_ATTR * N_ATTR * HC / 4);

  for (int l = 0; l < 2; l++) {
    const float* mt_bl_l  = mt_bl  + (size_t)l * HC;
    const float* ha_bl_l  = ha_bl  + (size_t)l * T_ATTR * HC;
    const unsigned short* Wts_l = Wts + (size_t)l * 27 * 16384;
    const unsigned short* Wct_l = Wct + (size_t)l * 16384;
    const float* biasc_l = biasc + (size_t)l * 128;

    // pre-transform GEMMs (MFMA, fp8 out -> gather tables)
    {
      MJobs J{};
      J.j[0] = {xdisb, Wts_l + 0 * 16384, nullptr, nullptr, nullptr, nullptr,
                (float*)Ydis8, nullptr, nullptr, N_DIS, 0, 2};
      for (int t = 0; t < T_ATTR; t++)
        J.j[1 + t] = {xab + (size_t)t * ATTR_S, Wts_l + (size_t)(1 + t) * 16384,
                      nullptr, nullptr, nullptr, nullptr,
                      (float*)(Yattr8 + (size_t)t * ATTR_S), nullptr, nullptr, N_ATTR, 0, 2};
      k_gemm_mfma<<<dim3((N_DIS + 63) / 64, 1, 9), b256, 0, stream>>>(J);
    }

    // gathers
    k_seg_mega<<<dim3((46000 + 3) / 4, 1, 1), b256, 0, stream>>>(
        off, wtab, vmd, vdrug, vhd, xd8, Ytab8, m2disb, accd, m2ab);

    // combine GEMMs (MFMA, f32 + bf16 + fp8 outs)
    {
      MJobs J{};
      J.j[0] = {xdb, Wct_l, nullptr, nullptr, biasc_l, accd, x_drug, xdb, xd8, N_DRUG, 1, 0};
      J.j[1] = {m2disb, Wts_l + 9 * 16384, xdisb, Wts_l + 10 * 16384, mt_bl_l, nullptr,
                x_dis, xdisb, nullptr, N_DIS, 1, 0};
      for (int t = 0; t < T_ATTR; t++)
        J.j[2 + t] = {m2ab + (size_t)t * ATTR_S, Wts_l + (size_t)(11 + t) * 16384,
                      xab + (size_t)t * ATTR_S, Wts_l + (size_t)(19 + t) * 16384,
                      ha_bl_l + (size_t)t * HC, nullptr, x_attr + (size_t)t * ATTR_S,
                      xab + (size_t)t * ATTR_S, nullptr, N_ATTR, 1, 0};
      k_gemm_mfma<<<dim3((N_DRUG + 63) / 64, 1, 10), b256, 0, stream>>>(J);
    }
  }

  // ---------- classifier ----------
  {
    G64Job ju = {x_drug, cw0, cb0, Ucls, N_DRUG};
    G64Job jv = {x_dis, cw0 + 128 * 64, nullptr, Vcls, N_DIS};
    k_gemm64<<<dim3((N_DRUG + 63) / 64, 1, 2), b256, 0, stream>>>(ju, jv);
    k_tail<<<dim3((2 * E_LBL + 255) / 256, 1, 1), b256, 0, stream>>>(
        Ucls, Vcls, ell_src, ell_dst,
        cw1, cb1, cw2, cb2, cw3, cb3, cw4, cb4, out, E_LBL);
  }
}

// Round 21
// 363.662 us; speedup vs baseline: 1.0378x; 1.0378x over previous
//
#include <hip/hip_runtime.h>
#include <hip/hip_fp16.h>

#define N_DRUG 20000
#define N_DIS  10000
#define N_ATTR 2000
#define T_ATTR 8
#define E_MT   500000
#define E_HA   100000
#define E_LBL  200000
#define HC     128
#define BPW    5000
#define NSS    46
#define NBMAX  80

__device__ __forceinline__ float leakyf(float x) { return x >= 0.f ? x : 0.01f * x; }

__device__ __forceinline__ unsigned short f2bf(float f) {
  unsigned int u = __float_as_uint(f);
  return (unsigned short)((u + 0x7fffu + ((u >> 16) & 1u)) >> 16);
}
__device__ __forceinline__ float bflo(unsigned int u) { return __uint_as_float(u << 16); }
__device__ __forceinline__ float bfhi(unsigned int u) { return __uint_as_float(u & 0xffff0000u); }

typedef __attribute__((ext_vector_type(8))) short bf16x8;
typedef __attribute__((ext_vector_type(4))) float f32x4;
typedef __attribute__((ext_vector_type(2))) float f32x2;

__device__ __forceinline__ unsigned int pk_fp8x4(float a, float b, float c, float d) {
  int w = 0;
  w = __builtin_amdgcn_cvt_pk_fp8_f32(a, b, w, false);
  w = __builtin_amdgcn_cvt_pk_fp8_f32(c, d, w, true);
  return (unsigned int)w;
}

// ---------------- CSR build ----------------
#define HB0 0
#define HB1 800000
#define HB2(t) (2400000 + (t) * 32000)
#define HB10(t) (2656000 + (t) * 320000)
#define HTOT 5216000
#define WB0 0
#define WB1 10000
#define WB2(t) (30000 + (t) * 2000)
#define WB10(t) (46000 + (t) * 20000)
#define WTOT 206000
#define OFF_Z0 0
#define OFF_D  10001
#define OFF_Z2(t) (190002 + (t) * 2001)
#define OFF_TOT 206010
#define SCH 2048
#define SMAXC 128

struct SegB { int bins; int hbase; int wbase; int obase; int ostride; int nbz; };
__device__ __forceinline__ SegB segb(int z) {
  SegB s;
  if (z == 0)      { s.bins = N_DIS;  s.hbase = HB0;  s.wbase = WB0;  s.obase = OFF_Z0;    s.ostride = 1; s.nbz = NBMAX; }
  else if (z == 1) { s.bins = N_DRUG; s.hbase = HB1;  s.wbase = WB1;  s.obase = OFF_D;     s.ostride = 9; s.nbz = NBMAX; }
  else if (z < 10) { int t = z - 2;  s.bins = N_ATTR; s.hbase = HB2(t);  s.wbase = WB2(t);  s.obase = OFF_Z2(t);   s.ostride = 1; s.nbz = 16; }
  else             { int t = z - 10; s.bins = N_DRUG; s.hbase = HB10(t); s.wbase = WB10(t); s.obase = OFF_D + 1 + t; s.ostride = 9; s.nbz = 16; }
  return s;
}

struct SegE { const int* key; const int* oth; int n; int roff; int* val; };
__device__ __forceinline__ SegE sege(int z,
    const int* mt_src, const int* mt_dst, const int* ha_src, const int* ha_dst,
    int* vmd, int* vdrug, int* vhd) {
  SegE s;
  if (z == 0)      { s.key = mt_dst; s.oth = mt_src; s.n = E_MT; s.roff = 0; s.val = vmd; }
  else if (z == 1) { s.key = mt_src; s.oth = mt_dst; s.n = E_MT; s.roff = 0; s.val = vdrug; }
  else if (z < 10) { int t = z - 2;
    s.key = ha_dst + (size_t)t * E_HA; s.oth = ha_src + (size_t)t * E_HA; s.n = E_HA;
    s.roff = 0; s.val = vhd + (size_t)t * E_HA; }
  else { int t = z - 10;
    s.key = ha_src + (size_t)t * E_HA; s.oth = ha_dst + (size_t)t * E_HA; s.n = E_HA;
    s.roff = 10000 + t * N_ATTR; s.val = vdrug; }
  return s;
}

__device__ __forceinline__ void ss_resolve(int ss, int& z, int& klo) {
  if (ss < 2)       { z = 0; klo = ss * BPW; }
  else if (ss < 6)  { z = 1; klo = (ss - 2) * BPW; }
  else if (ss < 14) { z = 2 + (ss - 6); klo = 0; }
  else              { z = 10 + ((ss - 14) >> 2); klo = ((ss - 14) & 3) * BPW; }
}

__global__ __launch_bounds__(256) void k_hist(
    const int* __restrict__ mt_src, const int* __restrict__ mt_dst,
    const int* __restrict__ ha_src, const int* __restrict__ ha_dst,
    int* __restrict__ hist) {
  int z, klo;
  ss_resolve(blockIdx.z, z, klo);
  SegB g = segb(z);
  int b = blockIdx.x;
  if (b >= g.nbz) return;
  SegE s = sege(z, mt_src, mt_dst, ha_src, ha_dst, nullptr, nullptr, nullptr);
  int window = min(BPW, g.bins - klo);
  __shared__ int h[BPW];
  int tid = threadIdx.x;
  for (int i = tid; i < window; i += 256) h[i] = 0;
  __syncthreads();
  int ch = (s.n + g.nbz - 1) / g.nbz;
  int lo = b * ch, hi = min(s.n, lo + ch);
  for (int i = lo + tid; i < hi; i += 256) {
    int r = s.key[i] - klo;
    if ((unsigned)r < (unsigned)window) atomicAdd(&h[r], 1);
  }
  __syncthreads();
  int* hz = hist + g.hbase + (size_t)b * g.bins + klo;
  for (int i = tid; i < window; i += 256) hz[i] = h[i];
}

__global__ __launch_bounds__(256) void k_blkpfx(int* __restrict__ hist, int* __restrict__ off,
                                                unsigned short* __restrict__ wtab) {
  SegB g = segb(blockIdx.z);
  int i = blockIdx.x * 256 + threadIdx.x;
  if (i >= g.bins) return;
  int run = 0;
  for (int b = 0; b < g.nbz; b++) {
    int idx = g.hbase + b * g.bins + i;
    int v = hist[idx];
    hist[idx] = run;
    run += v;
  }
  off[g.obase + i * g.ostride] = run;
  __half hw = __float2half(1.0f / (float)(run > 0 ? run : 1));
  wtab[g.wbase + i] = __half_as_ushort(hw);
}

__device__ __forceinline__ void scan_region(int r, int& base, int& L) {
  if (r == 0)      { base = OFF_Z0; L = 10000; }
  else if (r == 1) { base = OFF_D;  L = 180000; }
  else             { int t = r - 2; base = OFF_Z2(t); L = 2000; }
}

__global__ __launch_bounds__(256) void k_scan_l1(int* __restrict__ off, int* __restrict__ csum) {
  int base, L;
  scan_region(blockIdx.y, base, L);
  int c = blockIdx.x;
  int c0 = c * SCH;
  if (c0 >= L) return;
  int tid = threadIdx.x;
  int i0 = c0 + tid * 8;
  int v[8];
  int s = 0;
  #pragma unroll
  for (int j = 0; j < 8; j++) {
    int i = i0 + j;
    v[j] = (i < L) ? off[base + i] : 0;
    s += v[j];
  }
  __shared__ int ssum[256];
  ssum[tid] = s;
  __syncthreads();
  if (tid == 0) {
    int run = 0;
    #pragma unroll 8
    for (int i = 0; i < 256; i++) { int x = ssum[i]; ssum[i] = run; run += x; }
    csum[blockIdx.y * SMAXC + c] = run;
  }
  __syncthreads();
  int run = ssum[tid];
  #pragma unroll
  for (int j = 0; j < 8; j++) {
    int i = i0 + j;
    if (i < L) { off[base + i] = run; run += v[j]; }
  }
}

__global__ void k_scan_l2(int* __restrict__ off, int* __restrict__ csum) {
  int r = blockIdx.x;
  int base, L;
  scan_region(r, base, L);
  if (threadIdx.x == 0) {
    int nc = (L + SCH - 1) / SCH;
    int run = 0;
    for (int c = 0; c < nc; c++) {
      int v = csum[r * SMAXC + c];
      csum[r * SMAXC + c] = run;
      run += v;
    }
    off[base + L] = run;
  }
}

__global__ __launch_bounds__(256) void k_scan_l3(int* __restrict__ off, const int* __restrict__ csum) {
  int base, L;
  scan_region(blockIdx.y, base, L);
  int c = blockIdx.x;
  int c0 = c * SCH;
  if (c0 >= L || c == 0) return;
  int add = csum[blockIdx.y * SMAXC + c];
  int i0 = c0 + threadIdx.x * 8;
  #pragma unroll
  for (int j = 0; j < 8; j++) {
    int i = i0 + j;
    if (i < L) off[base + i] += add;
  }
}

__global__ __launch_bounds__(256) void k_fill2(
    const int* __restrict__ mt_src, const int* __restrict__ mt_dst,
    const int* __restrict__ ha_src, const int* __restrict__ ha_dst,
    const int* __restrict__ hist, const int* __restrict__ off,
    const unsigned short* __restrict__ wtab,
    int* vmd, int* vdrug, int* vhd) {
  int z, klo;
  ss_resolve(blockIdx.z, z, klo);
  SegB g = segb(z);
  int b = blockIdx.x;
  if (b >= g.nbz) return;
  SegE s = sege(z, mt_src, mt_dst, ha_src, ha_dst, vmd, vdrug, vhd);
  int window = min(BPW, g.bins - klo);
  __shared__ int h[BPW];
  __shared__ unsigned short hw[BPW];
  int tid = threadIdx.x;
  const int* hz = hist + g.hbase + (size_t)b * g.bins + klo;
  for (int i = tid; i < window; i += 256) {
    h[i] = hz[i] + off[g.obase + (klo + i) * g.ostride];
    hw[i] = wtab[g.wbase + klo + i];
  }
  __syncthreads();
  int ch = (s.n + g.nbz - 1) / g.nbz;
  int lo = b * ch, hi = min(s.n, lo + ch);
  for (int i = lo + tid; i < hi; i += 256) {
    int r = s.key[i] - klo;
    if ((unsigned)r < (unsigned)window) {
      int pos = atomicAdd(&h[r], 1);
      s.val[pos] = (int)(((unsigned int)hw[r] << 16) | (unsigned int)(s.oth[i] + s.roff));
    }
  }
}

// ---------------- x_dis init (dual f32 + bf16) ----------------
__global__ void k_dis0(const float* __restrict__ dx, const float* __restrict__ w,
                       const float* __restrict__ b, const float* __restrict__ emb,
                       float* __restrict__ out, unsigned short* __restrict__ outb) {
  int i = blockIdx.x;
  int j = threadIdx.x;
  float s = b[j] + emb[(size_t)i * HC + j];
  #pragma unroll
  for (int k = 0; k < 10; k++) s += dx[i * 10 + k] * w[k * HC + j];
  out[(size_t)i * HC + j] = s;
  outb[(size_t)i * HC + j] = f2bf(s);
}

// ---------------- Wct + biasc (both layers) ----------------
__global__ void k_wc(const float* __restrict__ rmt_wr, const float* __restrict__ rha_wr,
                     const float* __restrict__ rmt_bl, const float* __restrict__ rha_bl,
                     unsigned short* __restrict__ Wct, float* __restrict__ biasc) {
  int l = blockIdx.y;
  const float* wr_main = rmt_wr + (size_t)l * HC * HC;
  const float* wr_t = rha_wr + (size_t)l * T_ATTR * HC * HC;
  const float* bl_main = rmt_bl + (size_t)l * HC;
  const float* bl_t = rha_bl + (size_t)l * T_ATTR * HC;
  unsigned short* Wo = Wct + (size_t)l * 16384;
  float* bo = biasc + (size_t)l * 128;
  int i = blockIdx.x * blockDim.x + threadIdx.x;
  if (i < HC * HC) {
    float s = wr_main[i];
    #pragma unroll
    for (int t = 0; t < T_ATTR; t++) s += wr_t[(size_t)t * HC * HC + i];
    int k = i >> 7, n = i & 127;
    Wo[n * 128 + k] = f2bf(s);
  }
  if (i < HC) {
    float s = bl_main[i];
    #pragma unroll
    for (int t = 0; t < T_ATTR; t++) s += bl_t[t * HC + i];
    bo[i] = s;
  }
}

// ---------------- weight transpose f32 [128][128] -> bf16 Wt[n][k], 54 mats ----------------
struct WtJobs { const float* s[54]; };
__global__ __launch_bounds__(256) void k_wt(WtJobs J, unsigned short* __restrict__ dst) {
  const float* src = J.s[blockIdx.z];
  unsigned short* d = dst + (size_t)blockIdx.z * 16384;
  __shared__ float t[32][33];
  int tx = threadIdx.x & 31, ty = threadIdx.x >> 5;
  int i0 = blockIdx.x * 32, j0 = blockIdx.y * 32;
  #pragma unroll
  for (int q = 0; q < 4; q++) {
    int k = i0 + ty + q * 8;
    t[ty + q * 8][tx] = src[k * 128 + j0 + tx];
  }
  __syncthreads();
  #pragma unroll
  for (int q = 0; q < 4; q++) {
    int n = j0 + ty + q * 8;
    d[(size_t)n * 128 + i0 + tx] = f2bf(t[tx][ty + q * 8]);
  }
}

// ---------------- f32 -> bf16 convert ----------------
__global__ __launch_bounds__(256) void k_cvt(const float* __restrict__ src,
                                             unsigned short* __restrict__ dst, int n4) {
  int i = blockIdx.x * 256 + threadIdx.x;
  if (i >= n4) return;
  float4 v = ((const float4*)src)[i];
  uint2 w;
  w.x = (unsigned int)f2bf(v.x) | ((unsigned int)f2bf(v.y) << 16);
  w.y = (unsigned int)f2bf(v.z) | ((unsigned int)f2bf(v.w) << 16);
  ((uint2*)dst)[i] = w;
}

// ---------------- f32 -> bf16 + fp8 dual convert (one read) ----------------
__global__ __launch_bounds__(256) void k_cvt_dual(const float* __restrict__ src,
                                                  unsigned short* __restrict__ dstb,
                                                  unsigned char* __restrict__ dst8, int n4) {
  int i = blockIdx.x * 256 + threadIdx.x;
  if (i >= n4) return;
  float4 v = ((const float4*)src)[i];
  uint2 w;
  w.x = (unsigned int)f2bf(v.x) | ((unsigned int)f2bf(v.y) << 16);
  w.y = (unsigned int)f2bf(v.z) | ((unsigned int)f2bf(v.w) << 16);
  ((uint2*)dstb)[i] = w;
  ((unsigned int*)dst8)[i] = pk_fp8x4(v.x, v.y, v.z, v.w);
}

// ---------------- 2-edge-per-wave gather accumulators (fp8 tables) ----------------
__device__ __forceinline__ void gacc2_w(const unsigned char* __restrict__ T, const int* __restrict__ val,
                                        int b, int e, int lane31, int slot, f32x4& a) {
  int i = b;
  for (; i + 8 <= e; i += 8) {
    unsigned int pv[4], rv[4];
    #pragma unroll
    for (int q = 0; q < 4; q++) pv[q] = ((const unsigned int*)val)[i + 2 * q + slot];
    #pragma unroll
    for (int q = 0; q < 4; q++)
      rv[q] = *(const unsigned int*)(T + (size_t)(pv[q] & 0xffffu) * HC + lane31 * 4);
    #pragma unroll
    for (int q = 0; q < 4; q++) {
      float w = __half2float(__ushort_as_half((unsigned short)(pv[q] >> 16)));
      f32x2 lo = __builtin_amdgcn_cvt_pk_f32_fp8((int)rv[q], false);
      f32x2 hi = __builtin_amdgcn_cvt_pk_f32_fp8((int)rv[q], true);
      a.x = fmaf(w, lo.x, a.x); a.y = fmaf(w, lo.y, a.y);
      a.z = fmaf(w, hi.x, a.z); a.w = fmaf(w, hi.y, a.w);
    }
  }
  for (int j = i + slot; j < e; j += 2) {
    unsigned int pv = ((const unsigned int*)val)[j];
    unsigned int rv = *(const unsigned int*)(T + (size_t)(pv & 0xffffu) * HC + lane31 * 4);
    float w = __half2float(__ushort_as_half((unsigned short)(pv >> 16)));
    f32x2 lo = __builtin_amdgcn_cvt_pk_f32_fp8((int)rv, false);
    f32x2 hi = __builtin_amdgcn_cvt_pk_f32_fp8((int)rv, true);
    a.x = fmaf(w, lo.x, a.x); a.y = fmaf(w, lo.y, a.y);
    a.z = fmaf(w, hi.x, a.z); a.w = fmaf(w, hi.y, a.w);
  }
}

__device__ __forceinline__ void gacc2_u(const unsigned char* __restrict__ T, const int* __restrict__ val,
                                        int b, int e, int lane31, int slot, f32x4& a) {
  int i = b;
  for (; i + 8 <= e; i += 8) {
    unsigned int pv[4], rv[4];
    #pragma unroll
    for (int q = 0; q < 4; q++) pv[q] = ((const unsigned int*)val)[i + 2 * q + slot];
    #pragma unroll
    for (int q = 0; q < 4; q++)
      rv[q] = *(const unsigned int*)(T + (size_t)(pv[q] & 0xffffu) * HC + lane31 * 4);
    #pragma unroll
    for (int q = 0; q < 4; q++) {
      f32x2 lo = __builtin_amdgcn_cvt_pk_f32_fp8((int)rv[q], false);
      f32x2 hi = __builtin_amdgcn_cvt_pk_f32_fp8((int)rv[q], true);
      a.x += lo.x; a.y += lo.y; a.z += hi.x; a.w += hi.y;
    }
  }
  for (int j = i + slot; j < e; j += 2) {
    unsigned int pv = ((const unsigned int*)val)[j];
    unsigned int rv = *(const unsigned int*)(T + (size_t)(pv & 0xffffu) * HC + lane31 * 4);
    f32x2 lo = __builtin_amdgcn_cvt_pk_f32_fp8((int)rv, false);
    f32x2 hi = __builtin_amdgcn_cvt_pk_f32_fp8((int)rv, true);
    a.x += lo.x; a.y += lo.y; a.z += hi.x; a.w += hi.y;
  }
}

__device__ __forceinline__ void comb32(f32x4& a) {
  a.x += __shfl_xor(a.x, 32);
  a.y += __shfl_xor(a.y, 32);
  a.z += __shfl_xor(a.z, 32);
  a.w += __shfl_xor(a.w, 32);
}

// ---------------- mega segment-mean (drug waves first; fp8 tables; 2 edges/wave) ----------------
__global__ __launch_bounds__(256) void k_seg_mega(
    const int* __restrict__ off, const unsigned short* __restrict__ wtab,
    const int* __restrict__ vmd, const int* __restrict__ vdrug, const int* __restrict__ vhd,
    const unsigned char* __restrict__ xd8, const unsigned char* __restrict__ Ytab8,
    unsigned short* __restrict__ m2disb, float* __restrict__ accd, unsigned short* __restrict__ m2ab) {
  int lane = threadIdx.x & 63;
  int lane31 = lane & 31;
  int slot = lane >> 5;
  int w = blockIdx.x * 4 + (threadIdx.x >> 6);
  if (w < N_DRUG) {
    int d = w;
    int lo = off[OFF_D + d * 9], hi = off[OFF_D + d * 9 + 9];
    f32x4 a = {};
    gacc2_w(Ytab8, vdrug, lo, hi, lane31, slot, a);
    comb32(a);
    if (slot == 0)
      *(float4*)(accd + (size_t)d * HC + lane31 * 4) = make_float4(a.x, a.y, a.z, a.w);
  } else if (w < N_DRUG + N_DIS) {
    int d = w - N_DRUG;
    int lo = off[OFF_Z0 + d], hi = off[OFF_Z0 + d + 1];
    f32x4 a = {};
    gacc2_u(xd8, vmd, lo, hi, lane31, slot, a);
    comb32(a);
    if (slot == 0) {
      float wv = __half2float(__ushort_as_half(wtab[WB0 + d]));
      uint2 o;
      o.x = (unsigned int)f2bf(a.x * wv) | ((unsigned int)f2bf(a.y * wv) << 16);
      o.y = (unsigned int)f2bf(a.z * wv) | ((unsigned int)f2bf(a.w * wv) << 16);
      *(uint2*)(m2disb + (size_t)d * HC + lane31 * 4) = o;
    }
  } else {
    int idx = w - (N_DRUG + N_DIS);
    int t = idx / N_ATTR, r = idx - t * N_ATTR;
    int lo = off[OFF_Z2(t) + r], hi = off[OFF_Z2(t) + r + 1];
    f32x4 a = {};
    gacc2_u(xd8, vhd + (size_t)t * E_HA, lo, hi, lane31, slot, a);
    comb32(a);
    if (slot == 0) {
      float wv = __half2float(__ushort_as_half(wtab[WB2(t) + r]));
      uint2 o;
      o.x = (unsigned int)f2bf(a.x * wv) | ((unsigned int)f2bf(a.y * wv) << 16);
      o.y = (unsigned int)f2bf(a.z * wv) | ((unsigned int)f2bf(a.w * wv) << 16);
      *(uint2*)(m2ab + ((size_t)t * N_ATTR + r) * HC + lane31 * 4) = o;
    }
  }
}

// ---------------- MFMA GEMM ----------------
struct MJob {
  const unsigned short* X1; const unsigned short* Wt1;
  const unsigned short* X2; const unsigned short* Wt2;
  const float* bias; const float* ACC;
  float* D; unsigned short* D2; unsigned char* D3;
  int M; int leaky; int mode;
};
struct MJobs { MJob j[10]; };

__global__ __launch_bounds__(256) void k_gemm_mfma(MJobs jobs) {
  MJob jb = jobs.j[blockIdx.z];
  int m0 = blockIdx.x * 64;
  if (m0 >= jb.M) return;
  int wave = threadIdx.x >> 6;
  int lane = threadIdx.x & 63;
  int l15 = lane & 15, g = lane >> 4;
  int m = m0 + wave * 16 + l15;
  bool mok = m < jb.M;
  int mrow = mok ? m : 0;

  f32x4 acc[8] = {};
  #pragma unroll
  for (int part = 0; part < 2; part++) {
    const unsigned short* X = part ? jb.X2 : jb.X1;
    const unsigned short* Wt = part ? jb.Wt2 : jb.Wt1;
    if (!X) break;
    #pragma unroll
    for (int ks = 0; ks < 4; ks++) {
      int k0 = ks * 32 + g * 8;
      bf16x8 xb = {};
      if (mok) xb = *(const bf16x8*)(X + (size_t)mrow * 128 + k0);
      #pragma unroll
      for (int f = 0; f < 8; f++) {
        bf16x8 wb = *(const bf16x8*)(Wt + (size_t)(f * 16 + l15) * 128 + k0);
        acc[f] = __builtin_amdgcn_mfma_f32_16x16x32_bf16(wb, xb, acc[f], 0, 0, 0);
      }
    }
  }
  if (!mok) return;
  #pragma unroll
  for (int f = 0; f < 8; f++) {
    int n0 = f * 16 + 4 * g;
    float r0 = acc[f][0], r1 = acc[f][1], r2 = acc[f][2], r3 = acc[f][3];
    if (jb.bias) {
      float4 bs = *(const float4*)(jb.bias + n0);
      r0 += bs.x; r1 += bs.y; r2 += bs.z; r3 += bs.w;
    }
    if (jb.ACC) {
      float4 a = *(const float4*)(jb.ACC + (size_t)m * 128 + n0);
      r0 += a.x; r1 += a.y; r2 += a.z; r3 += a.w;
    }
    if (jb.leaky) { r0 = leakyf(r0); r1 = leakyf(r1); r2 = leakyf(r2); r3 = leakyf(r3); }
    if (jb.mode == 1) {
      unsigned short* Db = (unsigned short*)jb.D;
      uint2 w;
      w.x = (unsigned int)f2bf(r0) | ((unsigned int)f2bf(r1) << 16);
      w.y = (unsigned int)f2bf(r2) | ((unsigned int)f2bf(r3) << 16);
      *(uint2*)(Db + (size_t)m * 128 + n0) = w;
    } else if (jb.mode == 2) {
      *(unsigned int*)((unsigned char*)jb.D + (size_t)m * 128 + n0) = pk_fp8x4(r0, r1, r2, r3);
    } else {
      *(float4*)(jb.D + (size_t)m * 128 + n0) = make_float4(r0, r1, r2, r3);
      if (jb.D2) {
        uint2 w;
        w.x = (unsigned int)f2bf(r0) | ((unsigned int)f2bf(r1) << 16);
        w.y = (unsigned int)f2bf(r2) | ((unsigned int)f2bf(r3) << 16);
        *(uint2*)(jb.D2 + (size_t)m * 128 + n0) = w;
      }
      if (jb.D3) {
        *(unsigned int*)(jb.D3 + (size_t)m * 128 + n0) = pk_fp8x4(r0, r1, r2, r3);
      }
    }
  }
}

// ---------------- classifier head GEMMs (bf16 output for tail) ----------------
struct G64Job { const float* X; const float* W; const float* bias; unsigned short* D; int M; };

__global__ __launch_bounds__(256) void k_gemm64(G64Job j0, G64Job j1) {
  G64Job jb = blockIdx.z ? j1 : j0;
  int m0 = blockIdx.x * 64;
  if (m0 >= jb.M) return;
  __shared__ float As[16][68];
  __shared__ float Bs[16][68];
  int tid = threadIdx.x;
  int tx = tid & 15, ty = tid >> 4;
  float acc[4][4];
  #pragma unroll
  for (int i = 0; i < 4; i++)
    #pragma unroll
    for (int j = 0; j < 4; j++) acc[i][j] = 0.f;

  for (int kk = 0; kk < 128; kk += 16) {
    {
      int r = tid >> 2, kq = (tid & 3) * 4;
      int gr = m0 + r;
      float4 v = make_float4(0.f, 0.f, 0.f, 0.f);
      if (gr < jb.M) v = *(const float4*)(jb.X + (size_t)gr * HC + kk + kq);
      As[kq + 0][r] = v.x; As[kq + 1][r] = v.y; As[kq + 2][r] = v.z; As[kq + 3][r] = v.w;
    }
    {
      int k = tid >> 4, c = (tid & 15) * 4;
      *(float4*)&Bs[k][c] = *(const float4*)(jb.W + (size_t)(kk + k) * 64 + c);
    }
    __syncthreads();
    #pragma unroll
    for (int k = 0; k < 16; k++) {
      float4 a = *(const float4*)&As[k][ty * 4];
      float4 b = *(const float4*)&Bs[k][tx * 4];
      float av[4] = {a.x, a.y, a.z, a.w};
      float bb[4] = {b.x, b.y, b.z, b.w};
      #pragma unroll
      for (int i = 0; i < 4; i++)
        #pragma unroll
        for (int j = 0; j < 4; j++) acc[i][j] += av[i] * bb[j];
    }
    __syncthreads();
  }
  float4 bs = make_float4(0.f, 0.f, 0.f, 0.f);
  if (jb.bias) bs = *(const float4*)(jb.bias + tx * 4);
  #pragma unroll
  for (int i = 0; i < 4; i++) {
    int gr = m0 + ty * 4 + i;
    if (gr < jb.M) {
      uint2 w;
      w.x = (unsigned int)f2bf(acc[i][0] + bs.x) | ((unsigned int)f2bf(acc[i][1] + bs.y) << 16);
      w.y = (unsigned int)f2bf(acc[i][2] + bs.z) | ((unsigned int)f2bf(acc[i][3] + bs.w) << 16);
      *(uint2*)(jb.D + (size_t)gr * 64 + tx * 4) = w;
    }
  }
}

// ---------------- per-edge tail MLP (1 thread/edge, hoisted loads, LDS weights) ----------------
__global__ __launch_bounds__(256) void k_tail(
    const unsigned short* __restrict__ U, const unsigned short* __restrict__ V,
    const int* __restrict__ es, const int* __restrict__ ed,
    const float* __restrict__ cw1, const float* __restrict__ cb1,
    const float* __restrict__ cw2, const float* __restrict__ cb2,
    const float* __restrict__ cw3, const float* __restrict__ cb3,
    const float* __restrict__ cw4, const float* __restrict__ cb4,
    float* __restrict__ out, int n) {
  int tid = threadIdx.x;
  int i = blockIdx.x * 256 + tid;
  bool ok = i < n;
  int ii = ok ? i : 0;
  // hoisted: edge ids + full U/V rows (latency overlaps LDS staging + barrier)
  int s = es[ii], d = ed[ii];
  const uint4* up = (const uint4*)(U + (size_t)s * 64);
  const uint4* vp = (const uint4*)(V + (size_t)d * 64);
  uint4 ua[4], va[4];
  #pragma unroll
  for (int p = 0; p < 4; p++) { ua[p] = up[p]; va[p] = vp[p]; }

  __shared__ float w1[64 * 32];
  __shared__ float w2[32 * 16];
  __shared__ float w3[16 * 8];
  __shared__ float w4[8];
  __shared__ float b1[32], b2[16], b3[8];
  #pragma unroll
  for (int p = 0; p < 8; p++) w1[tid + p * 256] = cw1[tid + p * 256];
  #pragma unroll
  for (int p = 0; p < 2; p++) w2[tid + p * 256] = cw2[tid + p * 256];
  if (tid < 128) w3[tid] = cw3[tid];
  if (tid < 8)  w4[tid] = cw4[tid];
  if (tid < 32) b1[tid] = cb1[tid];
  if (tid < 16) b2[tid] = cb2[tid];
  if (tid < 8)  b3[tid] = cb3[tid];
  __syncthreads();
  if (!ok) return;

  // h1: 64 features from 8 hoisted uint4 (8 bf16 each)
  float h1[64];
  #pragma unroll
  for (int p = 0; p < 4; p++) {
    uint4 a = ua[p], b = va[p];
    h1[8 * p + 0] = leakyf(bflo(a.x) + bflo(b.x));
    h1[8 * p + 1] = leakyf(bfhi(a.x) + bfhi(b.x));
    h1[8 * p + 2] = leakyf(bflo(a.y) + bflo(b.y));
    h1[8 * p + 3] = leakyf(bfhi(a.y) + bfhi(b.y));
    h1[8 * p + 4] = leakyf(bflo(a.z) + bflo(b.z));
    h1[8 * p + 5] = leakyf(bfhi(a.z) + bfhi(b.z));
    h1[8 * p + 6] = leakyf(bflo(a.w) + bflo(b.w));
    h1[8 * p + 7] = leakyf(bfhi(a.w) + bfhi(b.w));
  }
  {
    const uint4* up2 = up + 4;
    const uint4* vp2 = vp + 4;
    #pragma unroll
    for (int p = 0; p < 4; p++) {
      uint4 a = up2[p], b = vp2[p];
      h1[32 + 8 * p + 0] = leakyf(bflo(a.x) + bflo(b.x));
      h1[32 + 8 * p + 1] = leakyf(bfhi(a.x) + bfhi(b.x));
      h1[32 + 8 * p + 2] = leakyf(bflo(a.y) + bflo(b.y));
      h1[32 + 8 * p + 3] = leakyf(bfhi(a.y) + bfhi(b.y));
      h1[32 + 8 * p + 4] = leakyf(bflo(a.z) + bflo(b.z));
      h1[32 + 8 * p + 5] = leakyf(bfhi(a.z) + bfhi(b.z));
      h1[32 + 8 * p + 6] = leakyf(bflo(a.w) + bflo(b.w));
      h1[32 + 8 * p + 7] = leakyf(bfhi(a.w) + bfhi(b.w));
    }
  }
  float h2[32];
  #pragma unroll
  for (int j = 0; j < 32; j++) h2[j] = b1[j];
  #pragma unroll
  for (int k = 0; k < 64; k++) {
    float hv = h1[k];
    #pragma unroll
    for (int jq = 0; jq < 8; jq++) {
      float4 w = *(const float4*)&w1[k * 32 + jq * 4];
      h2[4 * jq + 0] = fmaf(hv, w.x, h2[4 * jq + 0]);
      h2[4 * jq + 1] = fmaf(hv, w.y, h2[4 * jq + 1]);
      h2[4 * jq + 2] = fmaf(hv, w.z, h2[4 * jq + 2]);
      h2[4 * jq + 3] = fmaf(hv, w.w, h2[4 * jq + 3]);
    }
  }
  float h3[16];
  #pragma unroll
  for (int j = 0; j < 16; j++) h3[j] = b2[j];
  #pragma unroll
  for (int k = 0; k < 32; k++) {
    float hv = leakyf(h2[k]);
    #pragma unroll
    for (int jq = 0; jq < 4; jq++) {
      float4 w = *(const float4*)&w2[k * 16 + jq * 4];
      h3[4 * jq + 0] = fmaf(hv, w.x, h3[4 * jq + 0]);
      h3[4 * jq + 1] = fmaf(hv, w.y, h3[4 * jq + 1]);
      h3[4 * jq + 2] = fmaf(hv, w.z, h3[4 * jq + 2]);
      h3[4 * jq + 3] = fmaf(hv, w.w, h3[4 * jq + 3]);
    }
  }
  float h4[8];
  #pragma unroll
  for (int j = 0; j < 8; j++) h4[j] = b3[j];
  #pragma unroll
  for (int k = 0; k < 16; k++) {
    float hv = leakyf(h3[k]);
    #pragma unroll
    for (int jq = 0; jq < 2; jq++) {
      float4 w = *(const float4*)&w3[k * 8 + jq * 4];
      h4[4 * jq + 0] = fmaf(hv, w.x, h4[4 * jq + 0]);
      h4[4 * jq + 1] = fmaf(hv, w.y, h4[4 * jq + 1]);
      h4[4 * jq + 2] = fmaf(hv, w.z, h4[4 * jq + 2]);
      h4[4 * jq + 3] = fmaf(hv, w.w, h4[4 * jq + 3]);
    }
  }
  float p = cb4[0];
  #pragma unroll
  for (int k = 0; k < 8; k++) p = fmaf(leakyf(h4[k]), w4[k], p);
  out[i] = p;
}

extern "C" void kernel_launch(void* const* d_in, const int* in_sizes, int n_in,
                              void* d_out, int out_size, void* d_ws, size_t ws_size,
                              hipStream_t stream) {
  const float* disease_x   = (const float*)d_in[0];
  const float* drug_emb    = (const float*)d_in[1];
  const float* disease_emb = (const float*)d_in[2];
  const float* attr_emb    = (const float*)d_in[3];
  const float* dis_lin_w   = (const float*)d_in[4];
  const float* dis_lin_b   = (const float*)d_in[5];
  const float* mt_wl  = (const float*)d_in[6];
  const float* mt_bl  = (const float*)d_in[7];
  const float* mt_wr  = (const float*)d_in[8];
  const float* rmt_wl = (const float*)d_in[9];
  const float* rmt_bl = (const float*)d_in[10];
  const float* rmt_wr = (const float*)d_in[11];
  const float* ha_wl  = (const float*)d_in[12];
  const float* ha_bl  = (const float*)d_in[13];
  const float* ha_wr  = (const float*)d_in[14];
  const float* rha_wl = (const float*)d_in[15];
  const float* rha_bl = (const float*)d_in[16];
  const float* rha_wr = (const float*)d_in[17];
  const float* cw0 = (const float*)d_in[18];
  const float* cb0 = (const float*)d_in[19];
  const float* cw1 = (const float*)d_in[20];
  const float* cb1 = (const float*)d_in[21];
  const float* cw2 = (const float*)d_in[22];
  const float* cb2 = (const float*)d_in[23];
  const float* cw3 = (const float*)d_in[24];
  const float* cb3 = (const float*)d_in[25];
  const float* cw4 = (const float*)d_in[26];
  const float* cb4 = (const float*)d_in[27];
  const int* mt_src = (const int*)d_in[28];
  const int* mt_dst = (const int*)d_in[29];
  const int* ha_src = (const int*)d_in[30];
  const int* ha_dst = (const int*)d_in[31];
  const int* ell_src = (const int*)d_in[32];
  const int* ell_dst = (const int*)d_in[33];
  float* out = (float*)d_out;

  const long long ATTR_S = (long long)N_ATTR * HC;
  const long long W_S = HC * HC;

  // ---------- workspace carve ----------
  float* fws = (float*)d_ws;
  size_t o = 0;
  float* x_drug = fws + o; o += (size_t)N_DRUG * HC;
  float* x_dis  = fws + o; o += (size_t)N_DIS * HC;
  float* x_attr = fws + o; o += (size_t)T_ATTR * N_ATTR * HC;
  float* accd   = fws + o; o += (size_t)N_DRUG * HC;
  float* biasc  = fws + o; o += 256;
  unsigned short* Ucls = (unsigned short*)(fws + o); o += (size_t)N_DRUG * 64 / 2;
  unsigned short* Vcls = (unsigned short*)(fws + o); o += (size_t)N_DIS * 64 / 2;
  unsigned short* xdb    = (unsigned short*)(fws + o);
  unsigned short* xdisb  = xdb + (size_t)N_DRUG * HC;
  unsigned short* xab    = xdisb + (size_t)N_DIS * HC;
  unsigned short* m2disb = xab + (size_t)T_ATTR * N_ATTR * HC;
  unsigned short* m2ab   = m2disb + (size_t)N_DIS * HC;
  unsigned short* Wts    = m2ab + (size_t)T_ATTR * N_ATTR * HC;
  unsigned short* Wct    = Wts + 54 * 16384;
  unsigned char* Ytab8   = (unsigned char*)(Wct + 2 * 16384);
  unsigned char* Ydis8   = Ytab8;
  unsigned char* Yattr8  = Ytab8 + (size_t)N_DIS * HC;
  unsigned char* xd8     = Ytab8 + (size_t)(N_DIS + T_ATTR * N_ATTR) * HC;
  unsigned char* uchar_end = xd8 + (size_t)N_DRUG * HC;
  o += ((size_t)(uchar_end - (unsigned char*)xdb) + 3) / 4;
  int* iws = (int*)(fws + o);
  int* off = iws;
  int* vmd   = off + OFF_TOT;
  int* vdrug = vmd + E_MT;
  int* vhd   = vdrug + (E_MT + T_ATTR * E_HA);
  unsigned short* wtab = (unsigned short*)(vhd + (size_t)T_ATTR * E_HA);
  int* csum = (int*)(wtab + WTOT + (WTOT & 1));
  int* hist = (int*)fws;

  dim3 b256(256);
  // ---------- CSR build ----------
  k_hist<<<dim3(NBMAX, 1, NSS), b256, 0, stream>>>(mt_src, mt_dst, ha_src, ha_dst, hist);
  k_blkpfx<<<dim3((N_DRUG + 255) / 256, 1, 18), b256, 0, stream>>>(hist, off, wtab);
  {
    dim3 sg((180000 + SCH - 1) / SCH, 10);
    k_scan_l1<<<sg, b256, 0, stream>>>(off, csum);
    k_scan_l2<<<10, 64, 0, stream>>>(off, csum);
    k_scan_l3<<<sg, b256, 0, stream>>>(off, csum);
  }
  k_fill2<<<dim3(NBMAX, 1, NSS), b256, 0, stream>>>(mt_src, mt_dst, ha_src, ha_dst, hist, off, wtab,
                                                    vmd, vdrug, vhd);

  // ---------- weights (both layers, batched) ----------
  k_wc<<<dim3(64, 2), b256, 0, stream>>>(rmt_wr, rha_wr, rmt_bl, rha_bl, Wct, biasc);
  {
    WtJobs W{};
    for (int l = 0; l < 2; l++) {
      int base = l * 27;
      W.s[base + 0] = rmt_wl + (size_t)l * W_S;
      for (int t = 0; t < T_ATTR; t++) W.s[base + 1 + t] = rha_wl + (size_t)l * T_ATTR * W_S + (size_t)t * W_S;
      W.s[base + 9] = mt_wl + (size_t)l * W_S;
      W.s[base + 10] = mt_wr + (size_t)l * W_S;
      for (int t = 0; t < T_ATTR; t++) W.s[base + 11 + t] = ha_wl + (size_t)l * T_ATTR * W_S + (size_t)t * W_S;
      for (int t = 0; t < T_ATTR; t++) W.s[base + 19 + t] = ha_wr + (size_t)l * T_ATTR * W_S + (size_t)t * W_S;
    }
    k_wt<<<dim3(4, 4, 54), b256, 0, stream>>>(W, Wts);
  }

  // ---------- node init + initial bf16/fp8 copies ----------
  k_dis0<<<N_DIS, 128, 0, stream>>>(disease_x, dis_lin_w, dis_lin_b, disease_emb, x_dis, xdisb);
  k_cvt_dual<<<dim3((N_DRUG * HC / 4 + 255) / 256), b256, 0, stream>>>(drug_emb, xdb, xd8, N_DRUG * HC / 4);
  k_cvt<<<dim3((T_ATTR * N_ATTR * HC / 4 + 255) / 256), b256, 0, stream>>>(attr_emb, xab, T_ATTR * N_ATTR * HC / 4);

  for (int l = 0; l < 2; l++) {
    const float* mt_bl_l  = mt_bl  + (size_t)l * HC;
    const float* ha_bl_l  = ha_bl  + (size_t)l * T_ATTR * HC;
    const unsigned short* Wts_l = Wts + (size_t)l * 27 * 16384;
    const unsigned short* Wct_l = Wct + (size_t)l * 16384;
    const float* biasc_l = biasc + (size_t)l * 128;

    // pre-transform GEMMs (MFMA, fp8 out -> gather tables)
    {
      MJobs J{};
      J.j[0] = {xdisb, Wts_l + 0 * 16384, nullptr, nullptr, nullptr, nullptr,
                (float*)Ydis8, nullptr, nullptr, N_DIS, 0, 2};
      for (int t = 0; t < T_ATTR; t++)
        J.j[1 + t] = {xab + (size_t)t * ATTR_S, Wts_l + (size_t)(1 + t) * 16384,
                      nullptr, nullptr, nullptr, nullptr,
                      (float*)(Yattr8 + (size_t)t * ATTR_S), nullptr, nullptr, N_ATTR, 0, 2};
      k_gemm_mfma<<<dim3((N_DIS + 63) / 64, 1, 9), b256, 0, stream>>>(J);
    }

    // gathers
    k_seg_mega<<<dim3((46000 + 3) / 4, 1, 1), b256, 0, stream>>>(
        off, wtab, vmd, vdrug, vhd, xd8, Ytab8, m2disb, accd, m2ab);

    // combine GEMMs (MFMA, f32 + bf16 + fp8 outs)
    {
      MJobs J{};
      J.j[0] = {xdb, Wct_l, nullptr, nullptr, biasc_l, accd, x_drug, xdb, xd8, N_DRUG, 1, 0};
      J.j[1] = {m2disb, Wts_l + 9 * 16384, xdisb, Wts_l + 10 * 16384, mt_bl_l, nullptr,
                x_dis, xdisb, nullptr, N_DIS, 1, 0};
      for (int t = 0; t < T_ATTR; t++)
        J.j[2 + t] = {m2ab + (size_t)t * ATTR_S, Wts_l + (size_t)(11 + t) * 16384,
                      xab + (size_t)t * ATTR_S, Wts_l + (size_t)(19 + t) * 16384,
                      ha_bl_l + (size_t)t * HC, nullptr, x_attr + (size_t)t * ATTR_S,
                      xab + (size_t)t * ATTR_S, nullptr, N_ATTR, 1, 0};
      k_gemm_mfma<<<dim3((N_DRUG + 63) / 64, 1, 10), b256, 0, stream>>>(J);
    }
  }

  // ---------- classifier ----------
  {
    G64Job ju = {x_drug, cw0, cb0, Ucls, N_DRUG};
    G64Job jv = {x_dis, cw0 + 128 * 64, nullptr, Vcls, N_DIS};
    k_gemm64<<<dim3((N_DRUG + 63) / 64, 1, 2), b256, 0, stream>>>(ju, jv);
    k_tail<<<dim3((E_LBL + 255) / 256, 1, 1), b256, 0, stream>>>(
        Ucls, Vcls, ell_src, ell_dst,
        cw1, cb1, cw2, cb2, cw3, cb3, cw4, cb4, out, E_LBL);
  }
}